// Round 18
// baseline (228.145 us; speedup 1.0000x reference)
//
#include <hip/hip_runtime.h>
#include <math.h>

// ---------------- problem constants ----------------
#define NUM_CLASSES 80
#define TOPK 300
#define NTOT 10647             // 3*(169+676+2704)
#define L0END 507
#define L1END 2535
#define SELCAP 2048
#define CSTR 10656             // per-image cls stride: L0 [0,512) L1 [512,2540) L2 [2540,10652)
#define DELTA 0.25f            // near-max candidate window for exact sigmoid-argmax
#define NEARW 1e-3f            // m1-m2 gap below which sigf collision is possible

// level 0: 13x13 (mask 6,7,8), level 1: 26x26 (mask 3,4,5), level 2: 52x52 (mask 0,1,2)
__constant__ float ANCWf[3][3] = {{116.f,156.f,373.f},{30.f,62.f,59.f},{10.f,16.f,33.f}};
__constant__ float ANCHf[3][3] = {{90.f,198.f,326.f},{61.f,45.f,119.f},{13.f,30.f,23.f}};

// correctly-rounded f32 exp (f64 exp, rounded once) — matches numpy f32 exp
__device__ __forceinline__ float expcr(float x) { return (float)exp((double)x); }
// numpy-style f32 sigmoid: op-by-op 1/(1+exp(-x)), each op f32 correctly rounded
__device__ __forceinline__ float sigf(float x) {
    float e = expcr(-x);
    return __fdiv_rn(1.0f, __fadd_rn(1.0f, e));
}

// locate anchor idx -> level geometry + channel-0 pointer (stride hw between channels)
__device__ __forceinline__ const float* locate(const float* f0, const float* f1, const float* f2,
                                               int img, int idx,
                                               int& level, int& hw, int& W, int& hrow, int& wcol, int& a) {
    int local, cell;
    const float* base;
    if (idx < L0END) {
        level = 0; local = idx; hw = 169; W = 13;
        base = f0 + (size_t)img * 43095;        // 255*169
    } else if (idx < L1END) {
        level = 1; local = idx - L0END; hw = 676; W = 26;
        base = f1 + (size_t)img * 172380;       // 255*676
    } else {
        level = 2; local = idx - L1END; hw = 2704; W = 52;
        base = f2 + (size_t)img * 689520;       // 255*2704
    }
    a = local / hw; cell = local - a * hw;
    hrow = cell / W; wcol = cell - hrow * W;
    return base + (size_t)(a * 85) * hw + cell;
}

// exact first-wins sigmoid-argmax fallback (rare): first c with sigf(l_c)==smax
template <int HW>
__device__ __forceinline__ int argmax_fallback(const float* p, float m1, float smax) {
    for (int c = 0; c < NUM_CLASSES; ++c) {
        float v = p[(5 + c) * HW];
        if (v >= m1 - DELTA && sigf(v) == smax) return c;
    }
    return 0;
}

// one-anchor score/class (scalar path, used for L0): obj-gated early exit
// (sigf(obj)<0.5 => score<0.5 exactly since RN-mul by <=1.0 can't exceed sobj).
template <int HW>
__device__ __forceinline__ void score_anchor(const float* p, unsigned int idx,
                                             unsigned long long* kslot,
                                             unsigned char* cslot) {
    float e = expcr(-p[4 * HW]);
    float sobj = __fdiv_rn(1.0f, __fadd_rn(1.0f, e));
    if (sobj < 0.5f) { *kslot = 0ULL; return; }
    float m1 = p[5 * HW], m2 = -1e30f;
    int ci = 0;
    #pragma unroll 16
    for (int c = 1; c < NUM_CLASSES; ++c) {
        float v = p[(5 + c) * HW];
        if (v > m1) { m2 = m1; m1 = v; ci = c; }
        else m2 = fmaxf(m2, v);
    }
    float smax = sigf(m1);
    float s = __fmul_rn(sobj, smax);
    unsigned long long kv = 0ULL;
    if (s >= 0.5f)
        kv = ((unsigned long long)__float_as_uint(s) << 32) | (unsigned int)(~idx);
    *kslot = kv;
    if (s >= 0.5f) {
        int cid = ci;
        if (m2 >= m1 - NEARW || m1 > 8.0f)
            cid = argmax_fallback<HW>(p, m1, smax);
        *cslot = (unsigned char)cid;
    }
}

// two adjacent cells per thread (float2 loads, 16-deep explicit batches).
// m1=-1e30 init + strict-> scan from c=0 is bit-identical to init-with-c0.
template <int HW>
__device__ __forceinline__ void score_pair(const float* __restrict__ p, unsigned int idx0,
                                           unsigned long long* __restrict__ kslot,
                                           unsigned char* __restrict__ cslot) {
    float2 o2 = *(const float2*)(p + 4 * HW);
    float sa = __fdiv_rn(1.0f, __fadd_rn(1.0f, expcr(-o2.x)));
    float sb = __fdiv_rn(1.0f, __fadd_rn(1.0f, expcr(-o2.y)));
    if (sa < 0.5f && sb < 0.5f) { kslot[0] = 0ULL; kslot[1] = 0ULL; return; }

    float m1a = -1e30f, m2a = -1e30f, m1b = -1e30f, m2b = -1e30f;
    int cia = 0, cib = 0;
    for (int base = 0; base < NUM_CLASSES; base += 16) {   // 5 batches of 16
        float2 vv[16];
        #pragma unroll
        for (int j = 0; j < 16; ++j)
            vv[j] = *(const float2*)(p + (5 + base + j) * HW);
        #pragma unroll
        for (int j = 0; j < 16; ++j) {
            int c = base + j;
            float va = vv[j].x, vb = vv[j].y;
            if (va > m1a) { m2a = m1a; m1a = va; cia = c; } else m2a = fmaxf(m2a, va);
            if (vb > m1b) { m2b = m1b; m1b = vb; cib = c; } else m2b = fmaxf(m2b, vb);
        }
    }
    {   // cell 0
        float smax = sigf(m1a);
        float s = __fmul_rn(sa, smax);
        unsigned long long kv = 0ULL;
        if (s >= 0.5f)
            kv = ((unsigned long long)__float_as_uint(s) << 32) | (unsigned int)(~idx0);
        kslot[0] = kv;
        if (s >= 0.5f) {
            int cid = cia;
            if (m2a >= m1a - NEARW || m1a > 8.0f)
                cid = argmax_fallback<HW>(p, m1a, smax);
            cslot[0] = (unsigned char)cid;
        }
    }
    {   // cell 1
        float smax = sigf(m1b);
        float s = __fmul_rn(sb, smax);
        unsigned long long kv = 0ULL;
        if (s >= 0.5f)
            kv = ((unsigned long long)__float_as_uint(s) << 32) | (unsigned int)(~(idx0 + 1u));
        kslot[1] = kv;
        if (s >= 0.5f) {
            int cid = cib;
            if (m2b >= m1b - NEARW || m1b > 8.0f)
                cid = argmax_fallback<HW>(p + 1, m1b, smax);
            cslot[1] = (unsigned char)cid;
        }
    }
}

// ---------------- kernel 1: score — float2 per thread (L1/L2), scalar L0 ----------------
// Thread ranges:
//   L0 [0, 16384):          img=t>>9,  r=t&511,   valid r<507   (scalar)
//   L1 [16384, 49152):      img=tt>>10, g=tt&1023, valid g<1014 (3*338 float2 pairs)
//   L2 [49152, 180224):     img=tt>>12, g=tt&4095, valid g<4056 (3*1352 pairs)
__global__ void score_kernel(const float* __restrict__ f0, const float* __restrict__ f1,
                             const float* __restrict__ f2,
                             unsigned long long* __restrict__ keys,
                             unsigned char* __restrict__ cls8) {
    int t = blockIdx.x * blockDim.x + threadIdx.x;

    if (t < 16384) {
        int img = t >> 9;
        int r = t & 511;
        if (r < 507) {
            int a = r / 169, cell = r - a * 169;
            const float* p = f0 + (size_t)img * 43095 + (size_t)(a * 85) * 169 + cell;
            score_anchor<169>(p, (unsigned int)r,
                              keys + (size_t)img * NTOT + r,
                              cls8 + (size_t)img * CSTR + r);
        }
    } else if (t < 49152) {
        int tt = t - 16384;
        int img = tt >> 10;
        int g = tt & 1023;
        if (g < 1014) {
            int a = g / 338, grp = g - a * 338;
            int cell0 = grp * 2;
            int r = a * 676 + cell0;
            const float* p = f1 + (size_t)img * 172380 + (size_t)(a * 85) * 676 + cell0;
            score_pair<676>(p, (unsigned int)(L0END + r),
                            keys + (size_t)img * NTOT + L0END + r,
                            cls8 + (size_t)img * CSTR + 512 + r);
        }
    } else {
        int tt = t - 49152;
        int img = tt >> 12;
        int g = tt & 4095;
        if (g < 4056) {
            int a = g / 1352, grp = g - a * 1352;
            int cell0 = grp * 2;
            int r = a * 2704 + cell0;
            const float* p = f2 + (size_t)img * 689520 + (size_t)(a * 85) * 2704 + cell0;
            score_pair<2704>(p, (unsigned int)(L1END + r),
                             keys + (size_t)img * NTOT + L1END + r,
                             cls8 + (size_t)img * CSTR + 2540 + r);
        }
    }
}

// ---------------- kernel 2: top-300 — LDS-staged histogram select + exact rank ----------------
__global__ __launch_bounds__(1024) void topk_kernel(const unsigned long long* __restrict__ keys,
                                                    unsigned int* __restrict__ top_idx) {
    __shared__ unsigned long long s[NTOT];      // 85,176 B — staged keys
    __shared__ unsigned int hist[1024];
    __shared__ unsigned long long sel[SELCAP];  // 16 KiB
    __shared__ unsigned int wsum[16], wsuf[16];
    __shared__ unsigned int cnt;
    __shared__ int Tbin;

    int img = blockIdx.x;
    int tid = threadIdx.x;
    int wv = tid >> 6, ln = tid & 63;
    const unsigned long long* k = keys + (size_t)img * NTOT;

    hist[tid] = 0;
    if (tid == 0) { cnt = 0; Tbin = 0; }
    for (int i = tid; i < TOPK; i += 1024) top_idx[img * TOPK + i] = 0xFFFFFFFFu;
    __syncthreads();

    // stage + histogram in one global pass
    for (int i = tid; i < NTOT; i += 1024) {
        unsigned long long kv = k[i];
        s[i] = kv;
        unsigned int sb = (unsigned int)(kv >> 32);
        int bin = (int)(sb - 0x3F000000u) >> 13;   // negative for zero keys
        if (bin >= 0) {
            if (bin > 1023) bin = 1023;
            atomicAdd(&hist[bin], 1u);
        }
    }
    __syncthreads();

    // wave-level suffix scan of hist (scan[b] = sum_{b'>=b} hist[b'])
    unsigned int ssum = hist[tid];
    #pragma unroll
    for (int off = 1; off < 64; off <<= 1) {
        unsigned int o = __shfl_down(ssum, off, 64);
        if (ln + off < 64) ssum += o;
    }
    if (ln == 0) wsum[wv] = ssum;
    __syncthreads();
    if (wv == 0) {
        unsigned int tws = (ln < 16) ? wsum[ln] : 0u;
        #pragma unroll
        for (int off = 1; off < 16; off <<= 1) {
            unsigned int o = __shfl_down(tws, off, 64);
            if (ln + off < 16) tws += o;
        }
        if (ln < 16) wsuf[ln] = tws;   // wsuf[w] = sum over waves >= w
    }
    __syncthreads();
    {
        unsigned int higher = (wv < 15) ? wsuf[wv + 1] : 0u;
        unsigned int scanval = ssum + higher;                  // suffix sum from this bin
        unsigned int down1 = __shfl_down(scanval, 1, 64);
        unsigned int nextval = (ln < 63) ? down1 : higher;     // scan of bin+1 (tid=1023 -> 0)
        if (scanval >= TOPK && nextval < TOPK) Tbin = tid;     // unique transition
    }
    __syncthreads();
    int T = Tbin;

    // select from LDS: bin >= T
    for (int i = tid; i < NTOT; i += 1024) {
        unsigned long long kv = s[i];
        unsigned int sb = (unsigned int)(kv >> 32);
        int bin = (int)(sb - 0x3F000000u) >> 13;
        if (bin > 1023) bin = 1023;
        if (bin >= T) {
            unsigned int pos = atomicAdd(&cnt, 1u);
            if (pos < SELCAP) sel[pos] = kv;
        }
    }
    __syncthreads();
    int m = (int)cnt; if (m > SELCAP) m = SELCAP;

    // exact rank by pairwise comparison (keys unique), scatter rank < 300
    for (int i = tid; i < m; i += 1024) {
        unsigned long long ki = sel[i];
        int rank = 0;
        for (int j = 0; j < m; ++j) rank += (sel[j] > ki);
        if (rank < TOPK) top_idx[img * TOPK + rank] = ~((unsigned int)ki);
    }
}

// ---------------- kernel 3: slim decode + NMS (ballot bit-matrix + lane scan) ----------------
__global__ __launch_bounds__(1024) void nms_kernel(const float* __restrict__ f0,
                                                   const float* __restrict__ f1,
                                                   const float* __restrict__ f2,
                                                   const unsigned long long* __restrict__ keys,
                                                   const unsigned char* __restrict__ cls8,
                                                   const unsigned int* __restrict__ top_idx,
                                                   float* __restrict__ out) {
    __shared__ float bx0[TOPK], bx1[TOPK], bx2[TOPK], bx3[TOPK];
    __shared__ float bb0[TOPK], bb1[TOPK], bb2[TOPK], bb3[TOPK];
    __shared__ float area[TOPK], sc[TOPK], clsf[TOPK];
    __shared__ unsigned long long sup[TOPK][5];
    __shared__ unsigned long long keepm[5];

    int img = blockIdx.x;
    int tid = threadIdx.x;
    int wv = tid >> 6, ln = tid & 63;

    if (tid < TOPK) {
        unsigned int idx = top_idx[img * TOPK + tid];
        if (idx == 0xFFFFFFFFu) {
            bx0[tid] = 0.f; bx1[tid] = 0.f; bx2[tid] = 0.f; bx3[tid] = 0.f;
            bb0[tid] = 0.f; bb1[tid] = 0.f; bb2[tid] = 0.f; bb3[tid] = 0.f;
            area[tid] = 0.f; sc[tid] = 0.f; clsf[tid] = 0.f;
        } else {
            int level, hw, W, hrow, wcol, a;
            const float* p = locate(f0, f1, f2, img, (int)idx, level, hw, W, hrow, wcol, a);
            float tx = p[0];
            float ty = p[hw];
            float tw = p[2 * hw];
            float th = p[3 * hw];
            float score = __uint_as_float((unsigned int)(keys[(size_t)img * NTOT + idx] >> 32));
            int co = (idx < L0END) ? (int)idx
                     : (idx < L1END ? 512 + (int)idx - L0END : 2540 + (int)idx - L1END);
            int cid = cls8[(size_t)img * CSTR + co];

            float x = __fdiv_rn(__fadd_rn(sigf(tx), (float)wcol), (float)W);
            float y = __fdiv_rn(__fadd_rn(sigf(ty), (float)hrow), (float)W);   // H == W per level
            float wd = __fdiv_rn(__fmul_rn(expcr(tw), ANCWf[level][a]), 416.0f);
            float ht = __fdiv_rn(__fmul_rn(expcr(th), ANCHf[level][a]), 416.0f);

            float hx = __fmul_rn(wd, 0.5f);
            float hy = __fmul_rn(ht, 0.5f);
            float x1 = __fmul_rn(__fsub_rn(x, hx), 416.0f);
            float y1 = __fmul_rn(__fsub_rn(y, hy), 416.0f);
            float x2 = __fmul_rn(__fadd_rn(x, hx), 416.0f);
            float y2 = __fmul_rn(__fadd_rn(y, hy), 416.0f);
            float cf = (float)cid;
            float off = __fmul_rn(cf, 832.0f);   // 2*INPUT

            bx0[tid] = x1; bx1[tid] = y1; bx2[tid] = x2; bx3[tid] = y2;
            float b0 = __fadd_rn(x1, off), b1 = __fadd_rn(y1, off);
            float b2 = __fadd_rn(x2, off), b3 = __fadd_rn(y2, off);
            bb0[tid] = b0; bb1[tid] = b1; bb2[tid] = b2; bb3[tid] = b3;
            area[tid] = __fmul_rn(__fsub_rn(b2, b0), __fsub_rn(b3, b1));
            sc[tid] = score;
            clsf[tid] = cf;
        }
    }
    __syncthreads();

    // suppression bit-matrix, wave-parallel; lane's j-box kept in registers per w.
    #pragma unroll
    for (int w = 0; w < 5; ++w) {
        int j = (w << 6) + ln;
        bool jv = (j < TOPK);
        float j0 = jv ? bb0[j] : 0.0f;
        float j1 = jv ? bb1[j] : 0.0f;
        float j2 = jv ? bb2[j] : 0.0f;
        float j3 = jv ? bb3[j] : 0.0f;
        float ja = jv ? area[j] : 0.0f;
        for (int r = wv; r < TOPK; r += 16) {
            float a0 = bb0[r], a1 = bb1[r], a2 = bb2[r], a3 = bb3[r], aa = area[r];
            bool bit = false;
            if (jv && j > r) {
                float ltx = fmaxf(a0, j0);
                float lty = fmaxf(a1, j1);
                float rbx = fminf(a2, j2);
                float rby = fminf(a3, j3);
                float wx = fmaxf(__fsub_rn(rbx, ltx), 0.0f);
                float wy = fmaxf(__fsub_rn(rby, lty), 0.0f);
                float inter = __fmul_rn(wx, wy);
                float denom = __fadd_rn(__fsub_rn(__fadd_rn(aa, ja), inter), 1e-6f);
                float iou = __fdiv_rn(inter, denom);
                bit = (iou > 0.3f);
            }
            unsigned long long mm = __ballot(bit);
            if (ln == 0) sup[r][w] = mm;
        }
    }
    __syncthreads();

    // lane-parallel greedy scan by wave 0: lane w (w<5) owns keep-word kp.
    if (wv == 0) {
        unsigned long long kp = ~0ULL;
        for (int i = 0; i < TOPK; ++i) {
            unsigned long long kw = __shfl(kp, i >> 6, 64);
            bool keep_i = (kw >> (i & 63)) & 1ULL;
            if (keep_i && ln < 5) kp &= ~sup[i][ln];
        }
        if (ln < 5) keepm[ln] = kp;
    }
    __syncthreads();

    if (tid < TOPK) {
        bool kept = (keepm[tid >> 6] >> (tid & 63)) & 1ULL;
        float m = (kept && (sc[tid] > 0.0f)) ? 1.0f : 0.0f;
        float* o = out + ((size_t)img * TOPK + tid) * 6;
        o[0] = __fmul_rn(bx0[tid], m);
        o[1] = __fmul_rn(bx1[tid], m);
        o[2] = __fmul_rn(bx2[tid], m);
        o[3] = __fmul_rn(bx3[tid], m);
        o[4] = __fmul_rn(sc[tid], m);
        o[5] = __fmul_rn(clsf[tid], m);
    }
}

extern "C" void kernel_launch(void* const* d_in, const int* in_sizes, int n_in,
                              void* d_out, int out_size, void* d_ws, size_t ws_size,
                              hipStream_t stream) {
    const float* f0 = (const float*)d_in[0];
    const float* f1 = (const float*)d_in[1];
    const float* f2 = (const float*)d_in[2];
    float* out = (float*)d_out;

    int B = in_sizes[0] / 43095;   // 255*13*13 (== 32 for this problem)

    // workspace: [keys B*NTOT u64][cls8 B*CSTR u8][top_idx B*300 u32]
    unsigned long long* keys = (unsigned long long*)d_ws;
    size_t off1 = (size_t)B * NTOT * sizeof(unsigned long long);
    unsigned char* cls8 = (unsigned char*)d_ws + off1;
    size_t off2 = (off1 + (size_t)B * CSTR + 255) / 256 * 256;
    unsigned int* top_idx = (unsigned int*)((char*)d_ws + off2);

    // threads: 16384 (L0) + 32768 (L1) + 131072 (L2) = 180224
    score_kernel<<<180224 / 256, 256, 0, stream>>>(f0, f1, f2, keys, cls8);
    topk_kernel<<<B, 1024, 0, stream>>>(keys, top_idx);
    nms_kernel<<<B, 1024, 0, stream>>>(f0, f1, f2, keys, cls8, top_idx, out);
}

// Round 19
// 156.419 us; speedup vs baseline: 1.4586x; 1.4586x over previous
//
#include <hip/hip_runtime.h>
#include <math.h>

// ---------------- problem constants ----------------
#define NUM_CLASSES 80
#define TOPK 300
#define NTOT 10647             // 3*(169+676+2704)
#define L0END 507
#define L1END 2535
#define SELCAP 2048
#define CSTR 10656             // per-image cls stride: L0 [0,512) L1 [512,2540) L2 [2540,10652)
#define DELTA 0.25f            // near-max candidate window for exact sigmoid-argmax
#define NEARW 1e-3f            // m1-m2 gap below which sigf collision is possible

// level 0: 13x13 (mask 6,7,8), level 1: 26x26 (mask 3,4,5), level 2: 52x52 (mask 0,1,2)
__constant__ float ANCWf[3][3] = {{116.f,156.f,373.f},{30.f,62.f,59.f},{10.f,16.f,33.f}};
__constant__ float ANCHf[3][3] = {{90.f,198.f,326.f},{61.f,45.f,119.f},{13.f,30.f,23.f}};

// correctly-rounded f32 exp (f64 exp, rounded once) — matches numpy f32 exp
__device__ __forceinline__ float expcr(float x) { return (float)exp((double)x); }
// numpy-style f32 sigmoid: op-by-op 1/(1+exp(-x)), each op f32 correctly rounded
__device__ __forceinline__ float sigf(float x) {
    float e = expcr(-x);
    return __fdiv_rn(1.0f, __fadd_rn(1.0f, e));
}

// locate anchor idx -> level geometry + channel-0 pointer (stride hw between channels)
__device__ __forceinline__ const float* locate(const float* f0, const float* f1, const float* f2,
                                               int img, int idx,
                                               int& level, int& hw, int& W, int& hrow, int& wcol, int& a) {
    int local, cell;
    const float* base;
    if (idx < L0END) {
        level = 0; local = idx; hw = 169; W = 13;
        base = f0 + (size_t)img * 43095;        // 255*169
    } else if (idx < L1END) {
        level = 1; local = idx - L0END; hw = 676; W = 26;
        base = f1 + (size_t)img * 172380;       // 255*676
    } else {
        level = 2; local = idx - L1END; hw = 2704; W = 52;
        base = f2 + (size_t)img * 689520;       // 255*2704
    }
    a = local / hw; cell = local - a * hw;
    hrow = cell / W; wcol = cell - hrow * W;
    return base + (size_t)(a * 85) * hw + cell;
}

// exact first-wins sigmoid-argmax fallback (rare): first c with sigf(l_c)==smax
template <int HW>
__device__ __forceinline__ int argmax_fallback(const float* p, float m1, float smax) {
    for (int c = 0; c < NUM_CLASSES; ++c) {
        float v = p[(5 + c) * HW];
        if (v >= m1 - DELTA && sigf(v) == smax) return c;
    }
    return 0;
}

#define UPD(vr, cc) \
    if ((vr) > m1) { m2 = m1; m1 = (vr); ci = (cc); } else m2 = fmaxf(m2, (vr));

// one-anchor score/class: obj-gated early exit (sigf(obj)<0.5 => score<0.5 exactly,
// since RN-mul by sigf(mx)<=1.0 cannot exceed sigf(obj)); class scan in batches of
// 8 NAMED scalars (8 independent loads in flight, no spillable array). Scanning
// c=0..79 with m1=-1e30 init is bit-identical to init-with-c0 first-wins strict->.
template <int HW>
__device__ __forceinline__ void score_anchor(const float* p, unsigned int idx,
                                             unsigned long long* kslot,
                                             unsigned char* cslot) {
    float e = expcr(-p[4 * HW]);
    float sobj = __fdiv_rn(1.0f, __fadd_rn(1.0f, e));
    if (sobj < 0.5f) { *kslot = 0ULL; return; }
    float m1 = -1e30f, m2 = -1e30f;
    int ci = 0;
    #pragma unroll
    for (int base = 0; base < NUM_CLASSES; base += 8) {
        float v0 = p[(5 + base + 0) * HW];
        float v1 = p[(5 + base + 1) * HW];
        float v2 = p[(5 + base + 2) * HW];
        float v3 = p[(5 + base + 3) * HW];
        float v4 = p[(5 + base + 4) * HW];
        float v5 = p[(5 + base + 5) * HW];
        float v6 = p[(5 + base + 6) * HW];
        float v7 = p[(5 + base + 7) * HW];
        UPD(v0, base + 0); UPD(v1, base + 1); UPD(v2, base + 2); UPD(v3, base + 3);
        UPD(v4, base + 4); UPD(v5, base + 5); UPD(v6, base + 6); UPD(v7, base + 7);
    }
    float smax = sigf(m1);
    float s = __fmul_rn(sobj, smax);
    unsigned long long kv = 0ULL;
    if (s >= 0.5f)
        kv = ((unsigned long long)__float_as_uint(s) << 32) | (unsigned int)(~idx);
    *kslot = kv;
    if (s >= 0.5f) {
        int cid = ci;
        if (m2 >= m1 - NEARW || m1 > 8.0f)
            cid = argmax_fallback<HW>(p, m1, smax);
        *cslot = (unsigned char)cid;
    }
}

// ---------------- kernel 1: one thread per anchor, scalar coalesced loads ----------------
// Thread ranges (wave-aligned per image & level):
//   L0 [0, 16384):        img=t>>9,  r=t&511,  valid r<507  (3*169)
//   L1 [16384, 81920):    img=tt>>11, r=tt&2047, valid r<2028 (3*676)
//   L2 [81920, 344064):   img=tt>>13, r=tt&8191, valid r<8112 (3*2704)
__global__ void score_kernel(const float* __restrict__ f0, const float* __restrict__ f1,
                             const float* __restrict__ f2,
                             unsigned long long* __restrict__ keys,
                             unsigned char* __restrict__ cls8) {
    int t = blockIdx.x * blockDim.x + threadIdx.x;

    if (t < 16384) {
        int img = t >> 9;
        int r = t & 511;
        if (r < 507) {
            int a = r / 169, cell = r - a * 169;
            const float* p = f0 + (size_t)img * 43095 + (size_t)(a * 85) * 169 + cell;
            score_anchor<169>(p, (unsigned int)r,
                              keys + (size_t)img * NTOT + r,
                              cls8 + (size_t)img * CSTR + r);
        }
    } else if (t < 81920) {
        int tt = t - 16384;
        int img = tt >> 11;
        int r = tt & 2047;
        if (r < 2028) {
            int a = r / 676, cell = r - a * 676;
            const float* p = f1 + (size_t)img * 172380 + (size_t)(a * 85) * 676 + cell;
            score_anchor<676>(p, (unsigned int)(L0END + r),
                              keys + (size_t)img * NTOT + L0END + r,
                              cls8 + (size_t)img * CSTR + 512 + r);
        }
    } else {
        int tt = t - 81920;
        int img = tt >> 13;
        int r = tt & 8191;
        if (r < 8112) {
            int a = r / 2704, cell = r - a * 2704;
            const float* p = f2 + (size_t)img * 689520 + (size_t)(a * 85) * 2704 + cell;
            score_anchor<2704>(p, (unsigned int)(L1END + r),
                               keys + (size_t)img * NTOT + L1END + r,
                               cls8 + (size_t)img * CSTR + 2540 + r);
        }
    }
}

// ---------------- kernel 2: top-300 — LDS-staged histogram select + exact rank ----------------
__global__ __launch_bounds__(1024) void topk_kernel(const unsigned long long* __restrict__ keys,
                                                    unsigned int* __restrict__ top_idx) {
    __shared__ unsigned long long s[NTOT];      // 85,176 B — staged keys
    __shared__ unsigned int hist[1024];
    __shared__ unsigned long long sel[SELCAP];  // 16 KiB
    __shared__ unsigned int wsum[16], wsuf[16];
    __shared__ unsigned int cnt;
    __shared__ int Tbin;

    int img = blockIdx.x;
    int tid = threadIdx.x;
    int wv = tid >> 6, ln = tid & 63;
    const unsigned long long* k = keys + (size_t)img * NTOT;

    hist[tid] = 0;
    if (tid == 0) { cnt = 0; Tbin = 0; }
    for (int i = tid; i < TOPK; i += 1024) top_idx[img * TOPK + i] = 0xFFFFFFFFu;
    __syncthreads();

    // stage + histogram in one global pass
    for (int i = tid; i < NTOT; i += 1024) {
        unsigned long long kv = k[i];
        s[i] = kv;
        unsigned int sb = (unsigned int)(kv >> 32);
        int bin = (int)(sb - 0x3F000000u) >> 13;   // negative for zero keys
        if (bin >= 0) {
            if (bin > 1023) bin = 1023;
            atomicAdd(&hist[bin], 1u);
        }
    }
    __syncthreads();

    // wave-level suffix scan of hist (scan[b] = sum_{b'>=b} hist[b'])
    unsigned int ssum = hist[tid];
    #pragma unroll
    for (int off = 1; off < 64; off <<= 1) {
        unsigned int o = __shfl_down(ssum, off, 64);
        if (ln + off < 64) ssum += o;
    }
    if (ln == 0) wsum[wv] = ssum;
    __syncthreads();
    if (wv == 0) {
        unsigned int tws = (ln < 16) ? wsum[ln] : 0u;
        #pragma unroll
        for (int off = 1; off < 16; off <<= 1) {
            unsigned int o = __shfl_down(tws, off, 64);
            if (ln + off < 16) tws += o;
        }
        if (ln < 16) wsuf[ln] = tws;   // wsuf[w] = sum over waves >= w
    }
    __syncthreads();
    {
        unsigned int higher = (wv < 15) ? wsuf[wv + 1] : 0u;
        unsigned int scanval = ssum + higher;                  // suffix sum from this bin
        unsigned int down1 = __shfl_down(scanval, 1, 64);
        unsigned int nextval = (ln < 63) ? down1 : higher;     // scan of bin+1 (tid=1023 -> 0)
        if (scanval >= TOPK && nextval < TOPK) Tbin = tid;     // unique transition
    }
    __syncthreads();
    int T = Tbin;

    // select from LDS: bin >= T
    for (int i = tid; i < NTOT; i += 1024) {
        unsigned long long kv = s[i];
        unsigned int sb = (unsigned int)(kv >> 32);
        int bin = (int)(sb - 0x3F000000u) >> 13;
        if (bin > 1023) bin = 1023;
        if (bin >= T) {
            unsigned int pos = atomicAdd(&cnt, 1u);
            if (pos < SELCAP) sel[pos] = kv;
        }
    }
    __syncthreads();
    int m = (int)cnt; if (m > SELCAP) m = SELCAP;

    // exact rank by pairwise comparison (keys unique), scatter rank < 300
    for (int i = tid; i < m; i += 1024) {
        unsigned long long ki = sel[i];
        int rank = 0;
        for (int j = 0; j < m; ++j) rank += (sel[j] > ki);
        if (rank < TOPK) top_idx[img * TOPK + rank] = ~((unsigned int)ki);
    }
}

// ---------------- kernel 3: slim decode + NMS (ballot bit-matrix + lane scan) ----------------
__global__ __launch_bounds__(1024) void nms_kernel(const float* __restrict__ f0,
                                                   const float* __restrict__ f1,
                                                   const float* __restrict__ f2,
                                                   const unsigned long long* __restrict__ keys,
                                                   const unsigned char* __restrict__ cls8,
                                                   const unsigned int* __restrict__ top_idx,
                                                   float* __restrict__ out) {
    __shared__ float bx0[TOPK], bx1[TOPK], bx2[TOPK], bx3[TOPK];
    __shared__ float bb0[TOPK], bb1[TOPK], bb2[TOPK], bb3[TOPK];
    __shared__ float area[TOPK], sc[TOPK], clsf[TOPK];
    __shared__ unsigned long long sup[TOPK][5];
    __shared__ unsigned long long keepm[5];

    int img = blockIdx.x;
    int tid = threadIdx.x;
    int wv = tid >> 6, ln = tid & 63;

    if (tid < TOPK) {
        unsigned int idx = top_idx[img * TOPK + tid];
        if (idx == 0xFFFFFFFFu) {
            bx0[tid] = 0.f; bx1[tid] = 0.f; bx2[tid] = 0.f; bx3[tid] = 0.f;
            bb0[tid] = 0.f; bb1[tid] = 0.f; bb2[tid] = 0.f; bb3[tid] = 0.f;
            area[tid] = 0.f; sc[tid] = 0.f; clsf[tid] = 0.f;
        } else {
            int level, hw, W, hrow, wcol, a;
            const float* p = locate(f0, f1, f2, img, (int)idx, level, hw, W, hrow, wcol, a);
            float tx = p[0];
            float ty = p[hw];
            float tw = p[2 * hw];
            float th = p[3 * hw];
            float score = __uint_as_float((unsigned int)(keys[(size_t)img * NTOT + idx] >> 32));
            int co = (idx < L0END) ? (int)idx
                     : (idx < L1END ? 512 + (int)idx - L0END : 2540 + (int)idx - L1END);
            int cid = cls8[(size_t)img * CSTR + co];

            float x = __fdiv_rn(__fadd_rn(sigf(tx), (float)wcol), (float)W);
            float y = __fdiv_rn(__fadd_rn(sigf(ty), (float)hrow), (float)W);   // H == W per level
            float wd = __fdiv_rn(__fmul_rn(expcr(tw), ANCWf[level][a]), 416.0f);
            float ht = __fdiv_rn(__fmul_rn(expcr(th), ANCHf[level][a]), 416.0f);

            float hx = __fmul_rn(wd, 0.5f);
            float hy = __fmul_rn(ht, 0.5f);
            float x1 = __fmul_rn(__fsub_rn(x, hx), 416.0f);
            float y1 = __fmul_rn(__fsub_rn(y, hy), 416.0f);
            float x2 = __fmul_rn(__fadd_rn(x, hx), 416.0f);
            float y2 = __fmul_rn(__fadd_rn(y, hy), 416.0f);
            float cf = (float)cid;
            float off = __fmul_rn(cf, 832.0f);   // 2*INPUT

            bx0[tid] = x1; bx1[tid] = y1; bx2[tid] = x2; bx3[tid] = y2;
            float b0 = __fadd_rn(x1, off), b1 = __fadd_rn(y1, off);
            float b2 = __fadd_rn(x2, off), b3 = __fadd_rn(y2, off);
            bb0[tid] = b0; bb1[tid] = b1; bb2[tid] = b2; bb3[tid] = b3;
            area[tid] = __fmul_rn(__fsub_rn(b2, b0), __fsub_rn(b3, b1));
            sc[tid] = score;
            clsf[tid] = cf;
        }
    }
    __syncthreads();

    // suppression bit-matrix, wave-parallel; lane's j-box kept in registers per w.
    #pragma unroll
    for (int w = 0; w < 5; ++w) {
        int j = (w << 6) + ln;
        bool jv = (j < TOPK);
        float j0 = jv ? bb0[j] : 0.0f;
        float j1 = jv ? bb1[j] : 0.0f;
        float j2 = jv ? bb2[j] : 0.0f;
        float j3 = jv ? bb3[j] : 0.0f;
        float ja = jv ? area[j] : 0.0f;
        for (int r = wv; r < TOPK; r += 16) {
            float a0 = bb0[r], a1 = bb1[r], a2 = bb2[r], a3 = bb3[r], aa = area[r];
            bool bit = false;
            if (jv && j > r) {
                float ltx = fmaxf(a0, j0);
                float lty = fmaxf(a1, j1);
                float rbx = fminf(a2, j2);
                float rby = fminf(a3, j3);
                float wx = fmaxf(__fsub_rn(rbx, ltx), 0.0f);
                float wy = fmaxf(__fsub_rn(rby, lty), 0.0f);
                float inter = __fmul_rn(wx, wy);
                float denom = __fadd_rn(__fsub_rn(__fadd_rn(aa, ja), inter), 1e-6f);
                float iou = __fdiv_rn(inter, denom);
                bit = (iou > 0.3f);
            }
            unsigned long long mm = __ballot(bit);
            if (ln == 0) sup[r][w] = mm;
        }
    }
    __syncthreads();

    // lane-parallel greedy scan by wave 0: lane w (w<5) owns keep-word kp.
    if (wv == 0) {
        unsigned long long kp = ~0ULL;
        for (int i = 0; i < TOPK; ++i) {
            unsigned long long kw = __shfl(kp, i >> 6, 64);
            bool keep_i = (kw >> (i & 63)) & 1ULL;
            if (keep_i && ln < 5) kp &= ~sup[i][ln];
        }
        if (ln < 5) keepm[ln] = kp;
    }
    __syncthreads();

    if (tid < TOPK) {
        bool kept = (keepm[tid >> 6] >> (tid & 63)) & 1ULL;
        float m = (kept && (sc[tid] > 0.0f)) ? 1.0f : 0.0f;
        float* o = out + ((size_t)img * TOPK + tid) * 6;
        o[0] = __fmul_rn(bx0[tid], m);
        o[1] = __fmul_rn(bx1[tid], m);
        o[2] = __fmul_rn(bx2[tid], m);
        o[3] = __fmul_rn(bx3[tid], m);
        o[4] = __fmul_rn(sc[tid], m);
        o[5] = __fmul_rn(clsf[tid], m);
    }
}

extern "C" void kernel_launch(void* const* d_in, const int* in_sizes, int n_in,
                              void* d_out, int out_size, void* d_ws, size_t ws_size,
                              hipStream_t stream) {
    const float* f0 = (const float*)d_in[0];
    const float* f1 = (const float*)d_in[1];
    const float* f2 = (const float*)d_in[2];
    float* out = (float*)d_out;

    int B = in_sizes[0] / 43095;   // 255*13*13 (== 32 for this problem)

    // workspace: [keys B*NTOT u64][cls8 B*CSTR u8][top_idx B*300 u32]
    unsigned long long* keys = (unsigned long long*)d_ws;
    size_t off1 = (size_t)B * NTOT * sizeof(unsigned long long);
    unsigned char* cls8 = (unsigned char*)d_ws + off1;
    size_t off2 = (off1 + (size_t)B * CSTR + 255) / 256 * 256;
    unsigned int* top_idx = (unsigned int*)((char*)d_ws + off2);

    // threads: 16384 (L0) + 65536 (L1) + 262144 (L2) = 344064
    score_kernel<<<344064 / 256, 256, 0, stream>>>(f0, f1, f2, keys, cls8);
    topk_kernel<<<B, 1024, 0, stream>>>(keys, top_idx);
    nms_kernel<<<B, 1024, 0, stream>>>(f0, f1, f2, keys, cls8, top_idx, out);
}

// Round 20
// 103.963 us; speedup vs baseline: 2.1945x; 1.5046x over previous
//
#include <hip/hip_runtime.h>
#include <math.h>

// ---------------- problem constants ----------------
#define NUM_CLASSES 80
#define TOPK 300
#define NTOT 10647             // 3*(169+676+2704)
#define L0END 507
#define L1END 2535
#define SELCAP 2048
#define CSTR 10656             // per-image cls stride: L0 [0,512) L1 [512,2540) L2 [2540,10652)
#define DELTA 0.25f            // near-max candidate window for exact sigmoid-argmax
#define NEARW 1e-3f            // m1-m2 gap below which sigf collision is possible

// level 0: 13x13 (mask 6,7,8), level 1: 26x26 (mask 3,4,5), level 2: 52x52 (mask 0,1,2)
__constant__ float ANCWf[3][3] = {{116.f,156.f,373.f},{30.f,62.f,59.f},{10.f,16.f,33.f}};
__constant__ float ANCHf[3][3] = {{90.f,198.f,326.f},{61.f,45.f,119.f},{13.f,30.f,23.f}};

// correctly-rounded f32 exp (f64 exp, rounded once) — matches numpy f32 exp
__device__ __forceinline__ float expcr(float x) { return (float)exp((double)x); }
// numpy-style f32 sigmoid: op-by-op 1/(1+exp(-x)), each op f32 correctly rounded
__device__ __forceinline__ float sigf(float x) {
    float e = expcr(-x);
    return __fdiv_rn(1.0f, __fadd_rn(1.0f, e));
}

// locate anchor idx -> level geometry + channel-0 pointer (stride hw between channels)
__device__ __forceinline__ const float* locate(const float* f0, const float* f1, const float* f2,
                                               int img, int idx,
                                               int& level, int& hw, int& W, int& hrow, int& wcol, int& a) {
    int local, cell;
    const float* base;
    if (idx < L0END) {
        level = 0; local = idx; hw = 169; W = 13;
        base = f0 + (size_t)img * 43095;        // 255*169
    } else if (idx < L1END) {
        level = 1; local = idx - L0END; hw = 676; W = 26;
        base = f1 + (size_t)img * 172380;       // 255*676
    } else {
        level = 2; local = idx - L1END; hw = 2704; W = 52;
        base = f2 + (size_t)img * 689520;       // 255*2704
    }
    a = local / hw; cell = local - a * hw;
    hrow = cell / W; wcol = cell - hrow * W;
    return base + (size_t)(a * 85) * hw + cell;
}

// exact first-wins sigmoid-argmax fallback (rare): first c with sigf(l_c)==smax
template <int HW>
__device__ __forceinline__ int argmax_fallback(const float* p, float m1, float smax) {
    for (int c = 0; c < NUM_CLASSES; ++c) {
        float v = p[(5 + c) * HW];
        if (v >= m1 - DELTA && sigf(v) == smax) return c;
    }
    return 0;
}

#define UPD(vr, cc) \
    if ((vr) > m1) { m2 = m1; m1 = (vr); ci = (cc); } else m2 = fmaxf(m2, (vr));

// one-anchor score/class: obj-gated early exit; class scan in batches of 8 named
// scalars, outer loop NOT unrolled (#pragma unroll 1) so the scheduler cannot
// hoist all 80 loads (round-18/19 spill). Scanning c=0..79 with m1=-1e30 init is
// bit-identical to init-with-c0 first-wins strict->.
template <int HW>
__device__ __forceinline__ void score_anchor(const float* p, unsigned int idx,
                                             unsigned long long* kslot,
                                             unsigned char* cslot) {
    float e = expcr(-p[4 * HW]);
    float sobj = __fdiv_rn(1.0f, __fadd_rn(1.0f, e));
    if (sobj < 0.5f) { *kslot = 0ULL; return; }
    float m1 = -1e30f, m2 = -1e30f;
    int ci = 0;
    #pragma unroll 1
    for (int base = 0; base < NUM_CLASSES; base += 8) {
        float v0 = p[(5 + base + 0) * HW];
        float v1 = p[(5 + base + 1) * HW];
        float v2 = p[(5 + base + 2) * HW];
        float v3 = p[(5 + base + 3) * HW];
        float v4 = p[(5 + base + 4) * HW];
        float v5 = p[(5 + base + 5) * HW];
        float v6 = p[(5 + base + 6) * HW];
        float v7 = p[(5 + base + 7) * HW];
        UPD(v0, base + 0); UPD(v1, base + 1); UPD(v2, base + 2); UPD(v3, base + 3);
        UPD(v4, base + 4); UPD(v5, base + 5); UPD(v6, base + 6); UPD(v7, base + 7);
    }
    float smax = sigf(m1);
    float s = __fmul_rn(sobj, smax);
    unsigned long long kv = 0ULL;
    if (s >= 0.5f)
        kv = ((unsigned long long)__float_as_uint(s) << 32) | (unsigned int)(~idx);
    *kslot = kv;
    if (s >= 0.5f) {
        int cid = ci;
        if (m2 >= m1 - NEARW || m1 > 8.0f)
            cid = argmax_fallback<HW>(p, m1, smax);
        *cslot = (unsigned char)cid;
    }
}

// ---------------- kernel 1: one thread per anchor, scalar coalesced loads ----------------
// Thread ranges (wave-aligned per image & level):
//   L0 [0, 16384):        img=t>>9,  r=t&511,  valid r<507  (3*169)
//   L1 [16384, 81920):    img=tt>>11, r=tt&2047, valid r<2028 (3*676)
//   L2 [81920, 344064):   img=tt>>13, r=tt&8191, valid r<8112 (3*2704)
__global__ void score_kernel(const float* __restrict__ f0, const float* __restrict__ f1,
                             const float* __restrict__ f2,
                             unsigned long long* __restrict__ keys,
                             unsigned char* __restrict__ cls8) {
    int t = blockIdx.x * blockDim.x + threadIdx.x;

    if (t < 16384) {
        int img = t >> 9;
        int r = t & 511;
        if (r < 507) {
            int a = r / 169, cell = r - a * 169;
            const float* p = f0 + (size_t)img * 43095 + (size_t)(a * 85) * 169 + cell;
            score_anchor<169>(p, (unsigned int)r,
                              keys + (size_t)img * NTOT + r,
                              cls8 + (size_t)img * CSTR + r);
        }
    } else if (t < 81920) {
        int tt = t - 16384;
        int img = tt >> 11;
        int r = tt & 2047;
        if (r < 2028) {
            int a = r / 676, cell = r - a * 676;
            const float* p = f1 + (size_t)img * 172380 + (size_t)(a * 85) * 676 + cell;
            score_anchor<676>(p, (unsigned int)(L0END + r),
                              keys + (size_t)img * NTOT + L0END + r,
                              cls8 + (size_t)img * CSTR + 512 + r);
        }
    } else {
        int tt = t - 81920;
        int img = tt >> 13;
        int r = tt & 8191;
        if (r < 8112) {
            int a = r / 2704, cell = r - a * 2704;
            const float* p = f2 + (size_t)img * 689520 + (size_t)(a * 85) * 2704 + cell;
            score_anchor<2704>(p, (unsigned int)(L1END + r),
                               keys + (size_t)img * NTOT + L1END + r,
                               cls8 + (size_t)img * CSTR + 2540 + r);
        }
    }
}

// ---------------- kernel 2: top-300 — LDS-staged histogram select + exact rank ----------------
__global__ __launch_bounds__(1024) void topk_kernel(const unsigned long long* __restrict__ keys,
                                                    unsigned int* __restrict__ top_idx) {
    __shared__ unsigned long long s[NTOT];      // 85,176 B — staged keys
    __shared__ unsigned int hist[1024];
    __shared__ unsigned long long sel[SELCAP];  // 16 KiB
    __shared__ unsigned int wsum[16], wsuf[16];
    __shared__ unsigned int cnt;
    __shared__ int Tbin;

    int img = blockIdx.x;
    int tid = threadIdx.x;
    int wv = tid >> 6, ln = tid & 63;
    const unsigned long long* k = keys + (size_t)img * NTOT;

    hist[tid] = 0;
    if (tid == 0) { cnt = 0; Tbin = 0; }
    for (int i = tid; i < TOPK; i += 1024) top_idx[img * TOPK + i] = 0xFFFFFFFFu;
    __syncthreads();

    // stage + histogram in one global pass
    for (int i = tid; i < NTOT; i += 1024) {
        unsigned long long kv = k[i];
        s[i] = kv;
        unsigned int sb = (unsigned int)(kv >> 32);
        int bin = (int)(sb - 0x3F000000u) >> 13;   // negative for zero keys
        if (bin >= 0) {
            if (bin > 1023) bin = 1023;
            atomicAdd(&hist[bin], 1u);
        }
    }
    __syncthreads();

    // wave-level suffix scan of hist (scan[b] = sum_{b'>=b} hist[b'])
    unsigned int ssum = hist[tid];
    #pragma unroll
    for (int off = 1; off < 64; off <<= 1) {
        unsigned int o = __shfl_down(ssum, off, 64);
        if (ln + off < 64) ssum += o;
    }
    if (ln == 0) wsum[wv] = ssum;
    __syncthreads();
    if (wv == 0) {
        unsigned int tws = (ln < 16) ? wsum[ln] : 0u;
        #pragma unroll
        for (int off = 1; off < 16; off <<= 1) {
            unsigned int o = __shfl_down(tws, off, 64);
            if (ln + off < 16) tws += o;
        }
        if (ln < 16) wsuf[ln] = tws;   // wsuf[w] = sum over waves >= w
    }
    __syncthreads();
    {
        unsigned int higher = (wv < 15) ? wsuf[wv + 1] : 0u;
        unsigned int scanval = ssum + higher;                  // suffix sum from this bin
        unsigned int down1 = __shfl_down(scanval, 1, 64);
        unsigned int nextval = (ln < 63) ? down1 : higher;     // scan of bin+1 (tid=1023 -> 0)
        if (scanval >= TOPK && nextval < TOPK) Tbin = tid;     // unique transition
    }
    __syncthreads();
    int T = Tbin;

    // select from LDS: bin >= T
    for (int i = tid; i < NTOT; i += 1024) {
        unsigned long long kv = s[i];
        unsigned int sb = (unsigned int)(kv >> 32);
        int bin = (int)(sb - 0x3F000000u) >> 13;
        if (bin > 1023) bin = 1023;
        if (bin >= T) {
            unsigned int pos = atomicAdd(&cnt, 1u);
            if (pos < SELCAP) sel[pos] = kv;
        }
    }
    __syncthreads();
    int m = (int)cnt; if (m > SELCAP) m = SELCAP;

    // exact rank by pairwise comparison (keys unique), scatter rank < 300
    for (int i = tid; i < m; i += 1024) {
        unsigned long long ki = sel[i];
        int rank = 0;
        for (int j = 0; j < m; ++j) rank += (sel[j] > ki);
        if (rank < TOPK) top_idx[img * TOPK + rank] = ~((unsigned int)ki);
    }
}

// ---------------- kernel 3: slim decode + NMS (ballot bit-matrix + lane scan) ----------------
__global__ __launch_bounds__(1024) void nms_kernel(const float* __restrict__ f0,
                                                   const float* __restrict__ f1,
                                                   const float* __restrict__ f2,
                                                   const unsigned long long* __restrict__ keys,
                                                   const unsigned char* __restrict__ cls8,
                                                   const unsigned int* __restrict__ top_idx,
                                                   float* __restrict__ out) {
    __shared__ float bx0[TOPK], bx1[TOPK], bx2[TOPK], bx3[TOPK];
    __shared__ float bb0[TOPK], bb1[TOPK], bb2[TOPK], bb3[TOPK];
    __shared__ float area[TOPK], sc[TOPK], clsf[TOPK];
    __shared__ unsigned long long sup[TOPK][5];
    __shared__ unsigned long long keepm[5];

    int img = blockIdx.x;
    int tid = threadIdx.x;
    int wv = tid >> 6, ln = tid & 63;

    if (tid < TOPK) {
        unsigned int idx = top_idx[img * TOPK + tid];
        if (idx == 0xFFFFFFFFu) {
            bx0[tid] = 0.f; bx1[tid] = 0.f; bx2[tid] = 0.f; bx3[tid] = 0.f;
            bb0[tid] = 0.f; bb1[tid] = 0.f; bb2[tid] = 0.f; bb3[tid] = 0.f;
            area[tid] = 0.f; sc[tid] = 0.f; clsf[tid] = 0.f;
        } else {
            int level, hw, W, hrow, wcol, a;
            const float* p = locate(f0, f1, f2, img, (int)idx, level, hw, W, hrow, wcol, a);
            float tx = p[0];
            float ty = p[hw];
            float tw = p[2 * hw];
            float th = p[3 * hw];
            float score = __uint_as_float((unsigned int)(keys[(size_t)img * NTOT + idx] >> 32));
            int co = (idx < L0END) ? (int)idx
                     : (idx < L1END ? 512 + (int)idx - L0END : 2540 + (int)idx - L1END);
            int cid = cls8[(size_t)img * CSTR + co];

            float x = __fdiv_rn(__fadd_rn(sigf(tx), (float)wcol), (float)W);
            float y = __fdiv_rn(__fadd_rn(sigf(ty), (float)hrow), (float)W);   // H == W per level
            float wd = __fdiv_rn(__fmul_rn(expcr(tw), ANCWf[level][a]), 416.0f);
            float ht = __fdiv_rn(__fmul_rn(expcr(th), ANCHf[level][a]), 416.0f);

            float hx = __fmul_rn(wd, 0.5f);
            float hy = __fmul_rn(ht, 0.5f);
            float x1 = __fmul_rn(__fsub_rn(x, hx), 416.0f);
            float y1 = __fmul_rn(__fsub_rn(y, hy), 416.0f);
            float x2 = __fmul_rn(__fadd_rn(x, hx), 416.0f);
            float y2 = __fmul_rn(__fadd_rn(y, hy), 416.0f);
            float cf = (float)cid;
            float off = __fmul_rn(cf, 832.0f);   // 2*INPUT

            bx0[tid] = x1; bx1[tid] = y1; bx2[tid] = x2; bx3[tid] = y2;
            float b0 = __fadd_rn(x1, off), b1 = __fadd_rn(y1, off);
            float b2 = __fadd_rn(x2, off), b3 = __fadd_rn(y2, off);
            bb0[tid] = b0; bb1[tid] = b1; bb2[tid] = b2; bb3[tid] = b3;
            area[tid] = __fmul_rn(__fsub_rn(b2, b0), __fsub_rn(b3, b1));
            sc[tid] = score;
            clsf[tid] = cf;
        }
    }
    __syncthreads();

    // suppression bit-matrix, wave-parallel; lane's j-box kept in registers per w.
    #pragma unroll
    for (int w = 0; w < 5; ++w) {
        int j = (w << 6) + ln;
        bool jv = (j < TOPK);
        float j0 = jv ? bb0[j] : 0.0f;
        float j1 = jv ? bb1[j] : 0.0f;
        float j2 = jv ? bb2[j] : 0.0f;
        float j3 = jv ? bb3[j] : 0.0f;
        float ja = jv ? area[j] : 0.0f;
        for (int r = wv; r < TOPK; r += 16) {
            float a0 = bb0[r], a1 = bb1[r], a2 = bb2[r], a3 = bb3[r], aa = area[r];
            bool bit = false;
            if (jv && j > r) {
                float ltx = fmaxf(a0, j0);
                float lty = fmaxf(a1, j1);
                float rbx = fminf(a2, j2);
                float rby = fminf(a3, j3);
                float wx = fmaxf(__fsub_rn(rbx, ltx), 0.0f);
                float wy = fmaxf(__fsub_rn(rby, lty), 0.0f);
                float inter = __fmul_rn(wx, wy);
                float denom = __fadd_rn(__fsub_rn(__fadd_rn(aa, ja), inter), 1e-6f);
                float iou = __fdiv_rn(inter, denom);
                bit = (iou > 0.3f);
            }
            unsigned long long mm = __ballot(bit);
            if (ln == 0) sup[r][w] = mm;
        }
    }
    __syncthreads();

    // lane-parallel greedy scan by wave 0: lane w (w<5) owns keep-word kp.
    if (wv == 0) {
        unsigned long long kp = ~0ULL;
        for (int i = 0; i < TOPK; ++i) {
            unsigned long long kw = __shfl(kp, i >> 6, 64);
            bool keep_i = (kw >> (i & 63)) & 1ULL;
            if (keep_i && ln < 5) kp &= ~sup[i][ln];
        }
        if (ln < 5) keepm[ln] = kp;
    }
    __syncthreads();

    if (tid < TOPK) {
        bool kept = (keepm[tid >> 6] >> (tid & 63)) & 1ULL;
        float m = (kept && (sc[tid] > 0.0f)) ? 1.0f : 0.0f;
        float* o = out + ((size_t)img * TOPK + tid) * 6;
        o[0] = __fmul_rn(bx0[tid], m);
        o[1] = __fmul_rn(bx1[tid], m);
        o[2] = __fmul_rn(bx2[tid], m);
        o[3] = __fmul_rn(bx3[tid], m);
        o[4] = __fmul_rn(sc[tid], m);
        o[5] = __fmul_rn(clsf[tid], m);
    }
}

extern "C" void kernel_launch(void* const* d_in, const int* in_sizes, int n_in,
                              void* d_out, int out_size, void* d_ws, size_t ws_size,
                              hipStream_t stream) {
    const float* f0 = (const float*)d_in[0];
    const float* f1 = (const float*)d_in[1];
    const float* f2 = (const float*)d_in[2];
    float* out = (float*)d_out;

    int B = in_sizes[0] / 43095;   // 255*13*13 (== 32 for this problem)

    // workspace: [keys B*NTOT u64][cls8 B*CSTR u8][top_idx B*300 u32]
    unsigned long long* keys = (unsigned long long*)d_ws;
    size_t off1 = (size_t)B * NTOT * sizeof(unsigned long long);
    unsigned char* cls8 = (unsigned char*)d_ws + off1;
    size_t off2 = (off1 + (size_t)B * CSTR + 255) / 256 * 256;
    unsigned int* top_idx = (unsigned int*)((char*)d_ws + off2);

    // threads: 16384 (L0) + 65536 (L1) + 262144 (L2) = 344064
    score_kernel<<<344064 / 256, 256, 0, stream>>>(f0, f1, f2, keys, cls8);
    topk_kernel<<<B, 1024, 0, stream>>>(keys, top_idx);
    nms_kernel<<<B, 1024, 0, stream>>>(f0, f1, f2, keys, cls8, top_idx, out);
}